// Round 9
// baseline (29.714 us; speedup 1.0000x reference)
//
#include <hip/hip_runtime.h>

// ---------------- ws float offsets ----------------
enum : int {
  WS_H1 = 0,      // 64x128  composed node->f1 weight
  WS_H2 = 8192,   // 2x128   composed pos->f1 weight
  WS_H3 = 8448,   // 32x128  per-batch bias into f1 layer
  WS_END = 12544
};

// ---------------- K1: k_prep (96 blocks x 256) ----------------
// blocks 0..63:  H1/H2 columns, 2 per block; weights LDS-staged coalesced
// blocks 64..95: per-batch H3 chain (batch = blk-64)
__global__ __launch_bounds__(256) void k_prep(
    const float* __restrict__ h, const float* __restrict__ pos,
    const float* __restrict__ se_w, const float* __restrict__ se_b,
    const float* __restrict__ s1_w, const float* __restrict__ s1_b,
    const float* __restrict__ s2_w, const float* __restrict__ s2_b,
    const float* __restrict__ n1_w, const float* __restrict__ n1_b,
    const float* __restrict__ n2_w, const float* __restrict__ n2_b,
    const float* __restrict__ e1_w, const float* __restrict__ e1_b,
    const float* __restrict__ e2_w, const float* __restrict__ e2_b,
    const float* __restrict__ f1_w, const float* __restrict__ f1_b,
    float* __restrict__ ws)
{
  __shared__ __align__(16) float smem[9472];
  int blk = blockIdx.x, t = threadIdx.x;

  if (blk < 64) {
    // ---- H1/H2 column chain, 2 columns per block ----
    // H1[:,c] = 4*S1r@s2_w@n1_w@n2_w@E1r@e2_w@f1_w[:,c] ; H2[:,c] = -4*se_w@(S1e@v5)
    float* W  = smem;          // <= 128x65 (8320)
    float* VA = smem + 8320;   // [128][3]
    float* VB = smem + 8704;   // [128][3]
    float* PT = smem + 9088;   // [128][3]
    const int c0 = blk * 2;
    const int j = t & 1, rb = t >> 1;   // rb 0..127

    // stage a 128x64 weight into W padded [128][65]
    #define STAGE_W_128x64(ptr) \
      { _Pragma("unroll") for (int it = 0; it < 8; ++it) { \
          int i = t + it * 256; int row = i >> 4, col = (i & 15) * 4; \
          *(float4*)&W[row * 65 + col] = *(const float4*)((ptr) + row * 64 + col); } }
    // stage a 64x128 weight into W padded [64][129]
    #define STAGE_W_64x128(ptr) \
      { _Pragma("unroll") for (int it = 0; it < 8; ++it) { \
          int i = t + it * 256; int row = i >> 5, col = (i & 31) * 4; \
          *(float4*)&W[row * 129 + col] = *(const float4*)((ptr) + row * 128 + col); } }
    // out128 = W(128x64,p65) @ in64 ; 4 accumulators
    #define MUL_128x64(IN, OUT) \
      { float a0=0.f,a1=0.f,a2=0.f,a3=0.f; \
        _Pragma("unroll") for (int k = 0; k < 16; ++k) { \
          a0 = fmaf(W[rb*65 + k],      IN[(k)*3 + j],      a0); \
          a1 = fmaf(W[rb*65 + 16 + k], IN[(16 + k)*3 + j], a1); \
          a2 = fmaf(W[rb*65 + 32 + k], IN[(32 + k)*3 + j], a2); \
          a3 = fmaf(W[rb*65 + 48 + k], IN[(48 + k)*3 + j], a3); } \
        OUT[rb*3 + j] = (a0 + a1) + (a2 + a3); }
    // partial: out64 = W(64x128,p129) @ in128, k-split by rb>>6 -> PT
    #define MUL_64x128_PART(IN) \
      { float a0=0.f,a1=0.f,a2=0.f,a3=0.f; int r = rb & 63, kb = (rb >> 6) * 64; \
        _Pragma("unroll") for (int k = 0; k < 16; ++k) { \
          a0 = fmaf(W[r*129 + kb + k],      IN[(kb + k)*3 + j],      a0); \
          a1 = fmaf(W[r*129 + kb + 16 + k], IN[(kb + 16 + k)*3 + j], a1); \
          a2 = fmaf(W[r*129 + kb + 32 + k], IN[(kb + 32 + k)*3 + j], a2); \
          a3 = fmaf(W[r*129 + kb + 48 + k], IN[(kb + 48 + k)*3 + j], a3); } \
        PT[rb*3 + j] = (a0 + a1) + (a2 + a3); }

    // V0 = f1_w[:,c0..c0+1] ; stage W1 = e2_w (128x64)
    if (t < 128) { int k = t >> 1; VA[k * 3 + (t & 1)] = f1_w[k * 128 + c0 + (t & 1)]; }
    STAGE_W_128x64(e2_w);
    __syncthreads();
    MUL_128x64(VA, VB);                       // S1: VB = e2_w @ VA
    __syncthreads();
    STAGE_W_64x128(e1_w);                     // W = E1r
    __syncthreads();
    MUL_64x128_PART(VB);                      // S2 partial
    __syncthreads();
    if (rb < 64) VA[rb * 3 + j] = PT[rb * 3 + j] + PT[(rb + 64) * 3 + j];
    STAGE_W_128x64(n2_w);
    __syncthreads();
    MUL_128x64(VA, VB);                       // S3: VB = n2_w @ VA
    __syncthreads();
    STAGE_W_64x128(n1_w);
    __syncthreads();
    MUL_64x128_PART(VB);                      // S4 partial
    __syncthreads();
    if (rb < 64) VA[rb * 3 + j] = PT[rb * 3 + j] + PT[(rb + 64) * 3 + j];
    STAGE_W_128x64(s2_w);
    __syncthreads();
    MUL_128x64(VA, VB);                       // S5: VB = s2_w @ VA
    __syncthreads();
    STAGE_W_64x128(s1_w);                     // W = S1r (rows 0..63)
    __syncthreads();
    MUL_64x128_PART(VB);                      // S6a partial (H1)
    __syncthreads();
    if (rb < 64)
      ws[WS_H1 + rb * 128 + c0 + j] = 4.f * (PT[rb * 3 + j] + PT[(rb + 64) * 3 + j]);
    STAGE_W_64x128(s1_w + 128 * 128);         // W = S1e (rows 128..191)
    __syncthreads();
    MUL_64x128_PART(VB);                      // S6b partial (z)
    __syncthreads();
    if (rb < 64) VA[rb * 3 + j] = PT[rb * 3 + j] + PT[(rb + 64) * 3 + j];
    __syncthreads();
    // S7: H2[r2][c] = -4 * se_w[r2]@z
    if (t < 4) {
      int r2 = t >> 1, jj = t & 1;
      float a0 = 0.f, a1 = 0.f, a2 = 0.f, a3 = 0.f;
      #pragma unroll
      for (int k = 0; k < 16; ++k) {
        a0 = fmaf(se_w[r2 * 64 + k],      VA[(k) * 3 + jj],      a0);
        a1 = fmaf(se_w[r2 * 64 + 16 + k], VA[(16 + k) * 3 + jj], a1);
        a2 = fmaf(se_w[r2 * 64 + 32 + k], VA[(32 + k) * 3 + jj], a2);
        a3 = fmaf(se_w[r2 * 64 + 48 + k], VA[(48 + k) * 3 + jj], a3);
      }
      ws[WS_H2 + r2 * 128 + c0 + jj] = -4.f * ((a0 + a1) + (a2 + a3));
    }
    #undef STAGE_W_128x64
    #undef STAGE_W_64x128
    #undef MUL_128x64
    #undef MUL_64x128_PART
  } else {
    // ---- per-batch H3 chain (coalesced weight reads) ----
    int b = blk - 64;
    float* part = smem;        // 256
    float* sX = smem + 256;    // 64
    float* sP = smem + 320;    // 2
    float* L0 = smem + 384;    // 128
    float* L1 = smem + 512;    // 128
    float* L2 = smem + 640;    // 128
    float* L3 = smem + 768;    // 128
    float* M0 = smem + 896;    // 64
    float* M1 = smem + 960;    // 64
    { int k = t & 63, g = t >> 6; float s = 0.f;
      #pragma unroll 8
      for (int jn = g * 32; jn < g * 32 + 32; ++jn) s += h[(b * 128 + jn) * 64 + k];
      part[t] = s; }
    __syncthreads();
    if (t < 64) sX[t] = (part[t] + part[64 + t]) + (part[128 + t] + part[192 + t]);
    else if (t < 128) {
      int l = t - 64;
      const float* pb = pos + b * 256;
      float s = (pb[l] + pb[64 + l]) + (pb[128 + l] + pb[192 + l]);
      #pragma unroll
      for (int m = 2; m <= 32; m <<= 1) s += __shfl_xor(s, m, 64);
      if (l < 2) sP[l] = s;
    }
    __syncthreads();
    // Phase A: L0=xr=X@S1r, L1=k0=se_b@S1e+s1_b, L2=xs=X@S1s, L3=y=(P@se_w)@S1e
    { int g = t >> 7, o = t & 127;
      if (g == 0) {
        float a0 = 0.f, a1 = 0.f, k0 = 0.f, k1 = 0.f;
        #pragma unroll
        for (int k = 0; k < 32; ++k) {
          a0 = fmaf(sX[k],        s1_w[k * 128 + o],                a0);
          a1 = fmaf(sX[32 + k],   s1_w[(32 + k) * 128 + o],         a1);
          k0 = fmaf(se_b[k],      s1_w[(128 + k) * 128 + o],        k0);
          k1 = fmaf(se_b[32 + k], s1_w[(160 + k) * 128 + o],        k1);
        }
        L0[o] = a0 + a1; L1[o] = (k0 + k1) + s1_b[o];
      } else {
        float p0 = sP[0], p1 = sP[1];
        float a0 = 0.f, a1 = 0.f, y0 = 0.f, y1 = 0.f;
        #pragma unroll
        for (int k = 0; k < 32; ++k) {
          a0 = fmaf(sX[k],      s1_w[(64 + k) * 128 + o], a0);
          a1 = fmaf(sX[32 + k], s1_w[(96 + k) * 128 + o], a1);
          float qa = fmaf(p1, se_w[64 + k], p0 * se_w[k]);
          float qb = fmaf(p1, se_w[96 + k], p0 * se_w[32 + k]);
          y0 = fmaf(qa, s1_w[(128 + k) * 128 + o], y0);
          y1 = fmaf(qb, s1_w[(160 + k) * 128 + o], y1);
        }
        L2[o] = a0 + a1; L3[o] = y0 + y1;
      } }
    __syncthreads();
    // Phase B: M0 = v = ((xs+y)/64 + 2k0)@s2_w + 2*s2_b ; M1 = u = 2(xr-y)@s2_w
    if (t < 128) { int g = t >> 6, c = t & 63;
      float a0 = 0.f, a1 = 0.f;
      if (g == 0) {
        #pragma unroll
        for (int o = 0; o < 64; ++o) {
          float ra = fmaf(2.f, L1[o],      (L2[o] + L3[o]) * (1.f / 64.f));
          float rb2 = fmaf(2.f, L1[64 + o], (L2[64 + o] + L3[64 + o]) * (1.f / 64.f));
          a0 = fmaf(ra,  s2_w[o * 64 + c],        a0);
          a1 = fmaf(rb2, s2_w[(64 + o) * 64 + c], a1);
        }
        M0[c] = (a0 + a1) + 2.f * s2_b[c];
      } else {
        #pragma unroll
        for (int o = 0; o < 64; ++o) {
          a0 = fmaf(2.f * (L0[o] - L3[o]),           s2_w[o * 64 + c],        a0);
          a1 = fmaf(2.f * (L0[64 + o] - L3[64 + o]), s2_w[(64 + o) * 64 + c], a1);
        }
        M1[c] = a0 + a1;
      } }
    __syncthreads();
    // Phase C: L0 = v@n1_w + n1_b ; L1 = u@n1_w
    { int g = t >> 7, o = t & 127;
      float a0 = 0.f, a1 = 0.f;
      const float* mv = (g == 0) ? M0 : M1;
      #pragma unroll
      for (int k = 0; k < 32; ++k) {
        a0 = fmaf(mv[k],      n1_w[k * 128 + o],        a0);
        a1 = fmaf(mv[32 + k], n1_w[(32 + k) * 128 + o], a1);
      }
      if (g == 0) L0[o] = (a0 + a1) + n1_b[o]; else L1[o] = a0 + a1; }
    __syncthreads();
    // Phase D: M0 = c3 = L0@n2_w + n2_b ; M1 = un = L1@n2_w
    if (t < 128) { int g = t >> 6, c = t & 63;
      const float* lv = (g == 0) ? L0 : L1;
      float a0 = 0.f, a1 = 0.f;
      #pragma unroll
      for (int o = 0; o < 64; ++o) {
        a0 = fmaf(lv[o],      n2_w[o * 64 + c],        a0);
        a1 = fmaf(lv[64 + o], n2_w[(64 + o) * 64 + c], a1);
      }
      if (g == 0) M0[c] = (a0 + a1) + n2_b[c]; else M1[c] = a0 + a1; }
    __syncthreads();
    // Phase E: L0 = ce = c3@E1r ; L1 = ne = (un + 128*c3)@E1s
    { int g = t >> 7, o = t & 127;
      float a0 = 0.f, a1 = 0.f;
      if (g == 0) {
        #pragma unroll
        for (int k = 0; k < 32; ++k) {
          a0 = fmaf(M0[k],      e1_w[k * 128 + o],        a0);
          a1 = fmaf(M0[32 + k], e1_w[(32 + k) * 128 + o], a1);
        }
        L0[o] = a0 + a1;
      } else {
        #pragma unroll
        for (int k = 0; k < 32; ++k) {
          float na = fmaf(128.f, M0[k],      M1[k]);
          float nb = fmaf(128.f, M0[32 + k], M1[32 + k]);
          a0 = fmaf(na, e1_w[(64 + k) * 128 + o], a0);
          a1 = fmaf(nb, e1_w[(96 + k) * 128 + o], a1);
        }
        L1[o] = a0 + a1;
      } }
    __syncthreads();
    // Phase F: M0 = g3 = (2*ce + ne/64 + 2*e1_b)@e2_w + 2*e2_b
    if (t < 64) { float a0 = 0.f, a1 = 0.f;
      #pragma unroll
      for (int o = 0; o < 64; ++o) {
        float ga = fmaf(L1[o],      (1.f / 64.f), fmaf(2.f, L0[o],      2.f * e1_b[o]));
        float gb = fmaf(L1[64 + o], (1.f / 64.f), fmaf(2.f, L0[64 + o], 2.f * e1_b[64 + o]));
        a0 = fmaf(ga, e2_w[o * 64 + t],        a0);
        a1 = fmaf(gb, e2_w[(64 + o) * 64 + t], a1);
      }
      M0[t] = (a0 + a1) + 2.f * e2_b[t]; }
    __syncthreads();
    // Phase G: h3 = g3@f1_w + f1_b
    if (t < 128) { float a0 = 0.f, a1 = 0.f;
      #pragma unroll
      for (int k = 0; k < 32; ++k) {
        a0 = fmaf(M0[k],      f1_w[k * 128 + t],        a0);
        a1 = fmaf(M0[32 + k], f1_w[(32 + k) * 128 + t], a1);
      }
      ws[WS_H3 + b * 128 + t] = (a0 + a1) + f1_b[t]; }
  }
}

// ---------------- K2: per-node fused MLP (LDS ~44 KB) ----------------
__global__ __launch_bounds__(256) void k_main(
    const float* __restrict__ h, const float* __restrict__ pos,
    const float* __restrict__ f2_w, const float* __restrict__ f2_b,
    const float* __restrict__ ws, float* __restrict__ out)
{
  __shared__ __align__(16) float lH1[64 * 128];  // [k][d]  32 KB
  __shared__ __align__(16) float lx[16 * 64];    // [n][k]
  __shared__ float lp[16 * 2];
  __shared__ __align__(16) float lh1[16 * 128];  // [n][k]
  int blk = blockIdx.x, t = threadIdx.x;
  int b = blk >> 3, j0 = (blk & 7) * 16;
  for (int i = t; i < 2048; i += 256) ((float4*)lH1)[i] = ((const float4*)(ws + WS_H1))[i];
  ((float4*)lx)[t] = ((const float4*)(h + (size_t)(b * 128 + j0) * 64))[t];
  if (t < 32) lp[t] = pos[(b * 128 + j0) * 2 + t];
  __syncthreads();
  // h1 = relu(x@H1 + p@H2 + h3)   (H2/h3 broadcast reads straight from L1/L2)
  {
    int d = t & 127, g = t >> 7, n0 = g * 8;
    float h3v = ws[WS_H3 + b * 128 + d];
    float h2a = ws[WS_H2 + d], h2b = ws[WS_H2 + 128 + d];
    float acc[8];
    #pragma unroll
    for (int i = 0; i < 8; ++i)
      acc[i] = h3v + lp[(n0 + i) * 2] * h2a + lp[(n0 + i) * 2 + 1] * h2b;
    #pragma unroll 4
    for (int k = 0; k < 64; k += 4) {
      float h0 = lH1[k * 128 + d], h1v = lH1[(k + 1) * 128 + d],
            h2v = lH1[(k + 2) * 128 + d], h3w = lH1[(k + 3) * 128 + d];
      #pragma unroll
      for (int i = 0; i < 8; ++i) {
        float4 xv = *(const float4*)&lx[(n0 + i) * 64 + k];
        acc[i] = fmaf(xv.x, h0, fmaf(xv.y, h1v, fmaf(xv.z, h2v, fmaf(xv.w, h3w, acc[i]))));
      }
    }
    #pragma unroll
    for (int i = 0; i < 8; ++i) lh1[(n0 + i) * 128 + d] = fmaxf(acc[i], 0.f);
  }
  __syncthreads();
  // out = relu(h1@f2_w + f2_b); f2_w/f2_b read from global (L2-resident)
  {
    int d = t & 63, g = t >> 6, n0 = g * 4;
    float acc[4];
    float bias = f2_b[d];
    #pragma unroll
    for (int i = 0; i < 4; ++i) acc[i] = bias;
    #pragma unroll 4
    for (int k = 0; k < 128; k += 4) {
      float f0 = f2_w[k * 64 + d], f1v = f2_w[(k + 1) * 64 + d],
            f2v = f2_w[(k + 2) * 64 + d], f3v = f2_w[(k + 3) * 64 + d];
      #pragma unroll
      for (int i = 0; i < 4; ++i) {
        float4 hv = *(const float4*)&lh1[(n0 + i) * 128 + k];
        acc[i] = fmaf(hv.x, f0, fmaf(hv.y, f1v, fmaf(hv.z, f2v, fmaf(hv.w, f3v, acc[i]))));
      }
    }
    #pragma unroll
    for (int i = 0; i < 4; ++i)
      out[(size_t)(b * 128 + j0 + n0 + i) * 64 + d] = fmaxf(acc[i], 0.f);
  }
}

extern "C" void kernel_launch(void* const* d_in, const int* in_sizes, int n_in,
                              void* d_out, int out_size, void* d_ws, size_t ws_size,
                              hipStream_t stream) {
  const float* h    = (const float*)d_in[0];
  const float* pos  = (const float*)d_in[1];
  const float* se_w = (const float*)d_in[2];
  const float* se_b = (const float*)d_in[3];
  const float* s1_w = (const float*)d_in[4];
  const float* s1_b = (const float*)d_in[5];
  const float* s2_w = (const float*)d_in[6];
  const float* s2_b = (const float*)d_in[7];
  const float* n1_w = (const float*)d_in[8];
  const float* n1_b = (const float*)d_in[9];
  const float* n2_w = (const float*)d_in[10];
  const float* n2_b = (const float*)d_in[11];
  const float* e1_w = (const float*)d_in[12];
  const float* e1_b = (const float*)d_in[13];
  const float* e2_w = (const float*)d_in[14];
  const float* e2_b = (const float*)d_in[15];
  const float* f1_w = (const float*)d_in[16];
  const float* f1_b = (const float*)d_in[17];
  const float* f2_w = (const float*)d_in[18];
  const float* f2_b = (const float*)d_in[19];
  float* ws = (float*)d_ws;
  float* out = (float*)d_out;

  hipLaunchKernelGGL(k_prep, dim3(96), dim3(256), 0, stream,
                     h, pos, se_w, se_b, s1_w, s1_b, s2_w, s2_b,
                     n1_w, n1_b, n2_w, n2_b, e1_w, e1_b, e2_w, e2_b,
                     f1_w, f1_b, ws);
  hipLaunchKernelGGL(k_main, dim3(256), dim3(256), 0, stream, h, pos, f2_w, f2_b, ws, out);
}

// Round 10
// 29.593 us; speedup vs baseline: 1.0041x; 1.0041x over previous
//
#include <hip/hip_runtime.h>

// ---------------- ws float offsets ----------------
enum : int {
  WS_H1 = 0,      // 64x128  composed node->f1 weight
  WS_H2 = 8192,   // 2x128   composed pos->f1 weight
  WS_H3 = 8448,   // 32x128  per-batch bias into f1 layer
  WS_END = 12544
};

// ---------------- K1: k_prep (65 blocks x 256) ----------------
// blocks 0..31:  H1 rows 2b..2b+1, left-to-right GEMV chain (coalesced)
// block  32:     H2 rows (same chain, a2 prologue)
// blocks 33..64: per-batch H3 chain (batch = blk-33)
__global__ __launch_bounds__(256) void k_prep(
    const float* __restrict__ h, const float* __restrict__ pos,
    const float* __restrict__ se_w, const float* __restrict__ se_b,
    const float* __restrict__ s1_w, const float* __restrict__ s1_b,
    const float* __restrict__ s2_w, const float* __restrict__ s2_b,
    const float* __restrict__ n1_w, const float* __restrict__ n1_b,
    const float* __restrict__ n2_w, const float* __restrict__ n2_b,
    const float* __restrict__ e1_w, const float* __restrict__ e1_b,
    const float* __restrict__ e2_w, const float* __restrict__ e2_b,
    const float* __restrict__ f1_w, const float* __restrict__ f1_b,
    float* __restrict__ ws)
{
  __shared__ __align__(16) float smem[1024];
  int blk = blockIdx.x, t = threadIdx.x;

  if (blk < 33) {
    // ---- H1/H2 row chain: v0(128) @ s2_w @ n1_w @ n2_w @ E1r @ e2_w @ f1_w ----
    float (*v128)[128] = (float(*)[128])smem;         // 2x128
    float (*v64)[64]   = (float(*)[64])(smem + 256);  // 2x64
    float (*pt)[2][64] = (float(*)[2][64])(smem + 384); // 2x2x64
    const int row = t >> 7;          // 0..1
    const int c128 = t & 127;
    const int c64 = t & 63;
    const int half = (t >> 6) & 1;

    // v0: H1 rows = S1r rows; H2 rows = a2 = se_w @ S1e
    if (blk == 32) {
      float a0 = 0.f, a1 = 0.f;
      #pragma unroll
      for (int k = 0; k < 32; ++k) {
        a0 = fmaf(se_w[row * 64 + k],      s1_w[(128 + k) * 128 + c128], a0);
        a1 = fmaf(se_w[row * 64 + 32 + k], s1_w[(160 + k) * 128 + c128], a1);
      }
      v128[row][c128] = a0 + a1;
    } else {
      v128[row][c128] = s1_w[(blk * 2 + row) * 128 + c128];
    }
    __syncthreads();

    // 128 -> 64 stage: k-split halves, LDS combine
    #define STAGE_DN(W) \
      { float a0 = 0.f, a1 = 0.f; \
        _Pragma("unroll") for (int k = 0; k < 32; ++k) { \
          a0 = fmaf(v128[row][half * 64 + k],      (W)[(half * 64 + k) * 64 + c64],      a0); \
          a1 = fmaf(v128[row][half * 64 + 32 + k], (W)[(half * 64 + 32 + k) * 64 + c64], a1); } \
        pt[row][half][c64] = a0 + a1; } \
      __syncthreads(); \
      if (t < 128) v64[t >> 6][t & 63] = pt[t >> 6][0][t & 63] + pt[t >> 6][1][t & 63]; \
      __syncthreads();

    // 64 -> 128 stage
    #define STAGE_UP(W) \
      { float a0 = 0.f, a1 = 0.f; \
        _Pragma("unroll") for (int k = 0; k < 32; ++k) { \
          a0 = fmaf(v64[row][k],      (W)[k * 128 + c128],        a0); \
          a1 = fmaf(v64[row][32 + k], (W)[(32 + k) * 128 + c128], a1); } \
        v128[row][c128] = a0 + a1; } \
      __syncthreads();

    STAGE_DN(s2_w)    // v1 = v0 @ s2_w
    STAGE_UP(n1_w)    // v2 = v1 @ n1_w
    STAGE_DN(n2_w)    // v3 = v2 @ n2_w
    STAGE_UP(e1_w)    // v4 = v3 @ E1r (rows 0..63)
    STAGE_DN(e2_w)    // v5 = v4 @ e2_w
    // v6 = v5 @ f1_w ; write out
    { float a0 = 0.f, a1 = 0.f;
      #pragma unroll
      for (int k = 0; k < 32; ++k) {
        a0 = fmaf(v64[row][k],      f1_w[k * 128 + c128],        a0);
        a1 = fmaf(v64[row][32 + k], f1_w[(32 + k) * 128 + c128], a1);
      }
      float r = a0 + a1;
      if (blk == 32) ws[WS_H2 + row * 128 + c128] = -4.f * r;
      else           ws[WS_H1 + (blk * 2 + row) * 128 + c128] = 4.f * r;
    }
    #undef STAGE_DN
    #undef STAGE_UP
  } else {
    // ---- per-batch H3 chain (coalesced weight reads, 2-acc ILP) ----
    int b = blk - 33;
    float* part = smem;        // 256
    float* sX = smem + 256;    // 64
    float* sP = smem + 320;    // 2
    float* L0 = smem + 384;    // 128
    float* L1 = smem + 512;    // 128
    float* L2 = smem + 640;    // 128
    float* L3 = smem + 768;    // 128
    float* M0 = smem + 896;    // 64
    float* M1 = smem + 960;    // 64
    { int k = t & 63, g = t >> 6; float s = 0.f;
      #pragma unroll 8
      for (int jn = g * 32; jn < g * 32 + 32; ++jn) s += h[(b * 128 + jn) * 64 + k];
      part[t] = s; }
    __syncthreads();
    if (t < 64) sX[t] = (part[t] + part[64 + t]) + (part[128 + t] + part[192 + t]);
    else if (t < 128) {
      int l = t - 64;
      const float* pb = pos + b * 256;
      float s = (pb[l] + pb[64 + l]) + (pb[128 + l] + pb[192 + l]);
      #pragma unroll
      for (int m = 2; m <= 32; m <<= 1) s += __shfl_xor(s, m, 64);
      if (l < 2) sP[l] = s;
    }
    __syncthreads();
    // Phase A: L0=xr=X@S1r, L1=k0=se_b@S1e+s1_b, L2=xs=X@S1s, L3=y=(P@se_w)@S1e
    { int g = t >> 7, o = t & 127;
      if (g == 0) {
        float a0 = 0.f, a1 = 0.f, k0 = 0.f, k1 = 0.f;
        #pragma unroll
        for (int k = 0; k < 32; ++k) {
          a0 = fmaf(sX[k],        s1_w[k * 128 + o],         a0);
          a1 = fmaf(sX[32 + k],   s1_w[(32 + k) * 128 + o],  a1);
          k0 = fmaf(se_b[k],      s1_w[(128 + k) * 128 + o], k0);
          k1 = fmaf(se_b[32 + k], s1_w[(160 + k) * 128 + o], k1);
        }
        L0[o] = a0 + a1; L1[o] = (k0 + k1) + s1_b[o];
      } else {
        float p0 = sP[0], p1 = sP[1];
        float a0 = 0.f, a1 = 0.f, y0 = 0.f, y1 = 0.f;
        #pragma unroll
        for (int k = 0; k < 32; ++k) {
          a0 = fmaf(sX[k],      s1_w[(64 + k) * 128 + o], a0);
          a1 = fmaf(sX[32 + k], s1_w[(96 + k) * 128 + o], a1);
          float qa = fmaf(p1, se_w[64 + k], p0 * se_w[k]);
          float qb = fmaf(p1, se_w[96 + k], p0 * se_w[32 + k]);
          y0 = fmaf(qa, s1_w[(128 + k) * 128 + o], y0);
          y1 = fmaf(qb, s1_w[(160 + k) * 128 + o], y1);
        }
        L2[o] = a0 + a1; L3[o] = y0 + y1;
      } }
    __syncthreads();
    // Phase B: M0 = v = ((xs+y)/64 + 2k0)@s2_w + 2*s2_b ; M1 = u = 2(xr-y)@s2_w
    if (t < 128) { int g = t >> 6, c = t & 63;
      float a0 = 0.f, a1 = 0.f;
      if (g == 0) {
        #pragma unroll
        for (int o = 0; o < 64; ++o) {
          float ra  = fmaf(2.f, L1[o],      (L2[o] + L3[o]) * (1.f / 64.f));
          float rb2 = fmaf(2.f, L1[64 + o], (L2[64 + o] + L3[64 + o]) * (1.f / 64.f));
          a0 = fmaf(ra,  s2_w[o * 64 + c],        a0);
          a1 = fmaf(rb2, s2_w[(64 + o) * 64 + c], a1);
        }
        M0[c] = (a0 + a1) + 2.f * s2_b[c];
      } else {
        #pragma unroll
        for (int o = 0; o < 64; ++o) {
          a0 = fmaf(2.f * (L0[o] - L3[o]),           s2_w[o * 64 + c],        a0);
          a1 = fmaf(2.f * (L0[64 + o] - L3[64 + o]), s2_w[(64 + o) * 64 + c], a1);
        }
        M1[c] = a0 + a1;
      } }
    __syncthreads();
    // Phase C: L0 = v@n1_w + n1_b ; L1 = u@n1_w
    { int g = t >> 7, o = t & 127;
      float a0 = 0.f, a1 = 0.f;
      const float* mv = (g == 0) ? M0 : M1;
      #pragma unroll
      for (int k = 0; k < 32; ++k) {
        a0 = fmaf(mv[k],      n1_w[k * 128 + o],        a0);
        a1 = fmaf(mv[32 + k], n1_w[(32 + k) * 128 + o], a1);
      }
      if (g == 0) L0[o] = (a0 + a1) + n1_b[o]; else L1[o] = a0 + a1; }
    __syncthreads();
    // Phase D: M0 = c3 = L0@n2_w + n2_b ; M1 = un = L1@n2_w
    if (t < 128) { int g = t >> 6, c = t & 63;
      const float* lv = (g == 0) ? L0 : L1;
      float a0 = 0.f, a1 = 0.f;
      #pragma unroll
      for (int o = 0; o < 64; ++o) {
        a0 = fmaf(lv[o],      n2_w[o * 64 + c],        a0);
        a1 = fmaf(lv[64 + o], n2_w[(64 + o) * 64 + c], a1);
      }
      if (g == 0) M0[c] = (a0 + a1) + n2_b[c]; else M1[c] = a0 + a1; }
    __syncthreads();
    // Phase E: L0 = ce = c3@E1r ; L1 = ne = (un + 128*c3)@E1s
    { int g = t >> 7, o = t & 127;
      float a0 = 0.f, a1 = 0.f;
      if (g == 0) {
        #pragma unroll
        for (int k = 0; k < 32; ++k) {
          a0 = fmaf(M0[k],      e1_w[k * 128 + o],        a0);
          a1 = fmaf(M0[32 + k], e1_w[(32 + k) * 128 + o], a1);
        }
        L0[o] = a0 + a1;
      } else {
        #pragma unroll
        for (int k = 0; k < 32; ++k) {
          float na = fmaf(128.f, M0[k],      M1[k]);
          float nb = fmaf(128.f, M0[32 + k], M1[32 + k]);
          a0 = fmaf(na, e1_w[(64 + k) * 128 + o], a0);
          a1 = fmaf(nb, e1_w[(96 + k) * 128 + o], a1);
        }
        L1[o] = a0 + a1;
      } }
    __syncthreads();
    // Phase F: M0 = g3 = (2*ce + ne/64 + 2*e1_b)@e2_w + 2*e2_b
    if (t < 64) { float a0 = 0.f, a1 = 0.f;
      #pragma unroll
      for (int o = 0; o < 64; ++o) {
        float ga = fmaf(L1[o],      (1.f / 64.f), fmaf(2.f, L0[o],      2.f * e1_b[o]));
        float gb = fmaf(L1[64 + o], (1.f / 64.f), fmaf(2.f, L0[64 + o], 2.f * e1_b[64 + o]));
        a0 = fmaf(ga, e2_w[o * 64 + t],        a0);
        a1 = fmaf(gb, e2_w[(64 + o) * 64 + t], a1);
      }
      M0[t] = (a0 + a1) + 2.f * e2_b[t]; }
    __syncthreads();
    // Phase G: h3 = g3@f1_w + f1_b
    if (t < 128) { float a0 = 0.f, a1 = 0.f;
      #pragma unroll
      for (int k = 0; k < 32; ++k) {
        a0 = fmaf(M0[k],      f1_w[k * 128 + t],        a0);
        a1 = fmaf(M0[32 + k], f1_w[(32 + k) * 128 + t], a1);
      }
      ws[WS_H3 + b * 128 + t] = (a0 + a1) + f1_b[t]; }
  }
}

// ---------------- K2: per-node fused MLP (LDS ~44 KB) ----------------
__global__ __launch_bounds__(256) void k_main(
    const float* __restrict__ h, const float* __restrict__ pos,
    const float* __restrict__ f2_w, const float* __restrict__ f2_b,
    const float* __restrict__ ws, float* __restrict__ out)
{
  __shared__ __align__(16) float lH1[64 * 128];  // [k][d]  32 KB
  __shared__ __align__(16) float lx[16 * 64];    // [n][k]
  __shared__ float lp[16 * 2];
  __shared__ __align__(16) float lh1[16 * 128];  // [n][k]
  int blk = blockIdx.x, t = threadIdx.x;
  int b = blk >> 3, j0 = (blk & 7) * 16;
  for (int i = t; i < 2048; i += 256) ((float4*)lH1)[i] = ((const float4*)(ws + WS_H1))[i];
  ((float4*)lx)[t] = ((const float4*)(h + (size_t)(b * 128 + j0) * 64))[t];
  if (t < 32) lp[t] = pos[(b * 128 + j0) * 2 + t];
  __syncthreads();
  // h1 = relu(x@H1 + p@H2 + h3)   (H2/h3 broadcast reads straight from L1/L2)
  {
    int d = t & 127, g = t >> 7, n0 = g * 8;
    float h3v = ws[WS_H3 + b * 128 + d];
    float h2a = ws[WS_H2 + d], h2b = ws[WS_H2 + 128 + d];
    float acc[8];
    #pragma unroll
    for (int i = 0; i < 8; ++i)
      acc[i] = h3v + lp[(n0 + i) * 2] * h2a + lp[(n0 + i) * 2 + 1] * h2b;
    #pragma unroll 4
    for (int k = 0; k < 64; k += 4) {
      float h0 = lH1[k * 128 + d], h1v = lH1[(k + 1) * 128 + d],
            h2v = lH1[(k + 2) * 128 + d], h3w = lH1[(k + 3) * 128 + d];
      #pragma unroll
      for (int i = 0; i < 8; ++i) {
        float4 xv = *(const float4*)&lx[(n0 + i) * 64 + k];
        acc[i] = fmaf(xv.x, h0, fmaf(xv.y, h1v, fmaf(xv.z, h2v, fmaf(xv.w, h3w, acc[i]))));
      }
    }
    #pragma unroll
    for (int i = 0; i < 8; ++i) lh1[(n0 + i) * 128 + d] = fmaxf(acc[i], 0.f);
  }
  __syncthreads();
  // out = relu(h1@f2_w + f2_b); f2_w/f2_b read from global (L2-resident)
  {
    int d = t & 63, g = t >> 6, n0 = g * 4;
    float acc[4];
    float bias = f2_b[d];
    #pragma unroll
    for (int i = 0; i < 4; ++i) acc[i] = bias;
    #pragma unroll 4
    for (int k = 0; k < 128; k += 4) {
      float f0 = f2_w[k * 64 + d], f1v = f2_w[(k + 1) * 64 + d],
            f2v = f2_w[(k + 2) * 64 + d], f3v = f2_w[(k + 3) * 64 + d];
      #pragma unroll
      for (int i = 0; i < 4; ++i) {
        float4 hv = *(const float4*)&lh1[(n0 + i) * 128 + k];
        acc[i] = fmaf(hv.x, f0, fmaf(hv.y, f1v, fmaf(hv.z, f2v, fmaf(hv.w, f3v, acc[i]))));
      }
    }
    #pragma unroll
    for (int i = 0; i < 4; ++i)
      out[(size_t)(b * 128 + j0 + n0 + i) * 64 + d] = fmaxf(acc[i], 0.f);
  }
}

extern "C" void kernel_launch(void* const* d_in, const int* in_sizes, int n_in,
                              void* d_out, int out_size, void* d_ws, size_t ws_size,
                              hipStream_t stream) {
  const float* h    = (const float*)d_in[0];
  const float* pos  = (const float*)d_in[1];
  const float* se_w = (const float*)d_in[2];
  const float* se_b = (const float*)d_in[3];
  const float* s1_w = (const float*)d_in[4];
  const float* s1_b = (const float*)d_in[5];
  const float* s2_w = (const float*)d_in[6];
  const float* s2_b = (const float*)d_in[7];
  const float* n1_w = (const float*)d_in[8];
  const float* n1_b = (const float*)d_in[9];
  const float* n2_w = (const float*)d_in[10];
  const float* n2_b = (const float*)d_in[11];
  const float* e1_w = (const float*)d_in[12];
  const float* e1_b = (const float*)d_in[13];
  const float* e2_w = (const float*)d_in[14];
  const float* e2_b = (const float*)d_in[15];
  const float* f1_w = (const float*)d_in[16];
  const float* f1_b = (const float*)d_in[17];
  const float* f2_w = (const float*)d_in[18];
  const float* f2_b = (const float*)d_in[19];
  float* ws = (float*)d_ws;
  float* out = (float*)d_out;

  hipLaunchKernelGGL(k_prep, dim3(65), dim3(256), 0, stream,
                     h, pos, se_w, se_b, s1_w, s1_b, s2_w, s2_b,
                     n1_w, n1_b, n2_w, n2_b, e1_w, e1_b, e2_w, e2_b,
                     f1_w, f1_b, ws);
  hipLaunchKernelGGL(k_main, dim3(256), dim3(256), 0, stream, h, pos, f2_w, f2_b, ws, out);
}

// Round 11
// 27.449 us; speedup vs baseline: 1.0825x; 1.0781x over previous
//
#include <hip/hip_runtime.h>

// ---------------- ws float offsets ----------------
enum : int {
  WS_H1 = 0,      // 64x128  composed node->f1 weight
  WS_H2 = 8192,   // 2x128   composed pos->f1 weight
  WS_H3 = 8448,   // 32x128  per-batch bias into f1 layer
  WS_END = 12544
};

// ---------------- K1: k_prep (64 blocks x 256) ----------------
// blocks 0..31: H1/H2 columns, 4 per block (coalesced row-block layout)
// blocks 32..63: per-batch H3 chain (batch = blk-32)
__global__ __launch_bounds__(256) void k_prep(
    const float* __restrict__ h, const float* __restrict__ pos,
    const float* __restrict__ se_w, const float* __restrict__ se_b,
    const float* __restrict__ s1_w, const float* __restrict__ s1_b,
    const float* __restrict__ s2_w, const float* __restrict__ s2_b,
    const float* __restrict__ n1_w, const float* __restrict__ n1_b,
    const float* __restrict__ n2_w, const float* __restrict__ n2_b,
    const float* __restrict__ e1_w, const float* __restrict__ e1_b,
    const float* __restrict__ e2_w, const float* __restrict__ e2_b,
    const float* __restrict__ f1_w, const float* __restrict__ f1_b,
    float* __restrict__ ws)
{
  __shared__ __align__(16) float smem[1280];
  int blk = blockIdx.x, t = threadIdx.x;

  if (blk < 32) {
    // ---- H1/H2 column chain, 4 columns per block ----
    // H1[:,c] = 4*S1r@s2_w@n1_w@n2_w@E1r@e2_w@f1_w[:,c] ; H2[:,c] = -4*se_w@(S1e@v5)
    float* VA = smem;         // [128][5]
    float* VB = smem + 640;   // [128][5]
    const int c0 = blk * 4;
    const int j = t & 3, rb = t >> 2;   // rb 0..63
    if (t < 256) { int k = t >> 2, jj = t & 3;   // V0 = f1_w[:,c0..c0+3] (64x4)
      VA[k * 5 + jj] = f1_w[k * 128 + c0 + jj];
    }
    __syncthreads();
    // S1: VB(128) = e2_w @ VA(64)
    { float a0 = 0.f, a1 = 0.f;
      #pragma unroll 16
      for (int k = 0; k < 64; ++k) {
        float v = VA[k*5 + j];
        a0 = fmaf(e2_w[rb*64 + k],      v, a0);
        a1 = fmaf(e2_w[(rb+64)*64 + k], v, a1);
      }
      VB[rb*5+j] = a0; VB[(rb+64)*5+j] = a1; }
    __syncthreads();
    // S2: VA(64) = E1r @ VB(128)
    { float a = 0.f;
      #pragma unroll 16
      for (int k = 0; k < 128; ++k) a = fmaf(e1_w[rb*128 + k], VB[k*5 + j], a);
      VA[rb*5+j] = a; }
    __syncthreads();
    // S3: VB(128) = n2_w @ VA(64)
    { float a0 = 0.f, a1 = 0.f;
      #pragma unroll 16
      for (int k = 0; k < 64; ++k) {
        float v = VA[k*5 + j];
        a0 = fmaf(n2_w[rb*64 + k],      v, a0);
        a1 = fmaf(n2_w[(rb+64)*64 + k], v, a1);
      }
      VB[rb*5+j] = a0; VB[(rb+64)*5+j] = a1; }
    __syncthreads();
    // S4: VA(64) = n1_w @ VB(128)
    { float a = 0.f;
      #pragma unroll 16
      for (int k = 0; k < 128; ++k) a = fmaf(n1_w[rb*128 + k], VB[k*5 + j], a);
      VA[rb*5+j] = a; }
    __syncthreads();
    // S5: VB(128) = s2_w @ VA(64)
    { float a0 = 0.f, a1 = 0.f;
      #pragma unroll 16
      for (int k = 0; k < 64; ++k) {
        float v = VA[k*5 + j];
        a0 = fmaf(s2_w[rb*64 + k],      v, a0);
        a1 = fmaf(s2_w[(rb+64)*64 + k], v, a1);
      }
      VB[rb*5+j] = a0; VB[(rb+64)*5+j] = a1; }
    __syncthreads();
    // S6: H1 row rb = 4*S1r[rb]@VB ; z[rb] = S1e[rb]@VB (into VA)
    { float a = 0.f, z = 0.f;
      #pragma unroll 16
      for (int k = 0; k < 128; ++k) {
        float v = VB[k*5 + j];
        a = fmaf(s1_w[rb*128 + k],       v, a);
        z = fmaf(s1_w[(128+rb)*128 + k], v, z);
      }
      ws[WS_H1 + rb*128 + c0 + j] = 4.f * a;
      VA[rb*5+j] = z; }
    __syncthreads();
    // S7: H2[r2][c] = -4 * se_w[r2]@z
    if (t < 8) {
      int r2 = t >> 2, jj = t & 3;
      float a = 0.f;
      #pragma unroll 16
      for (int k = 0; k < 64; ++k) a = fmaf(se_w[r2*64 + k], VA[k*5 + jj], a);
      ws[WS_H2 + r2*128 + c0 + jj] = -4.f * a;
    }
  } else {
    // ---- per-batch H3 chain ----
    int b = blk - 32;
    float* part = smem;        // 256
    float* sX = smem + 256;    // 64
    float* sP = smem + 320;    // 2
    float* L0 = smem + 384;    // 128
    float* L1 = smem + 512;    // 128
    float* L2 = smem + 640;    // 128
    float* L3 = smem + 768;    // 128
    float* M0 = smem + 896;    // 64
    float* M1 = smem + 960;    // 64
    { int k = t & 63, g = t >> 6; float s = 0.f;
      #pragma unroll 8
      for (int jn = g * 32; jn < g * 32 + 32; ++jn) s += h[(b * 128 + jn) * 64 + k];
      part[t] = s; }
    __syncthreads();
    if (t < 64) sX[t] = (part[t] + part[64 + t]) + (part[128 + t] + part[192 + t]);
    else if (t < 128) {
      // pos sums: lane l of wave 1; flat idx b*256 + 64m + l, 4 coalesced loads
      int l = t - 64;
      const float* pb = pos + b * 256;
      float s = (pb[l] + pb[64 + l]) + (pb[128 + l] + pb[192 + l]);
      #pragma unroll
      for (int m = 2; m <= 32; m <<= 1) s += __shfl_xor(s, m, 64);
      if (l < 2) sP[l] = s;
    }
    __syncthreads();
    // Phase A: L0=xr=X@S1r, L1=k0=se_b@S1e+s1_b, L2=xs=X@S1s, L3=y=(P@se_w)@S1e
    { int g = t >> 7, o = t & 127;
      if (g == 0) {
        float a = 0.f, kk = 0.f;
        #pragma unroll
        for (int k = 0; k < 64; ++k) {
          a  = fmaf(sX[k],   s1_w[k * 128 + o],         a);
          kk = fmaf(se_b[k], s1_w[(128 + k) * 128 + o], kk);
        }
        L0[o] = a; L1[o] = kk + s1_b[o];
      } else {
        float p0 = sP[0], p1 = sP[1];
        float a = 0.f, yy = 0.f;
        #pragma unroll
        for (int k = 0; k < 64; ++k) {
          a = fmaf(sX[k], s1_w[(64 + k) * 128 + o], a);
          float qk = fmaf(p1, se_w[64 + k], p0 * se_w[k]);
          yy = fmaf(qk, s1_w[(128 + k) * 128 + o], yy);
        }
        L2[o] = a; L3[o] = yy;
      } }
    __syncthreads();
    // Phase B: M0 = v = ((xs+y)/64 + 2k0)@s2_w + 2*s2_b ; M1 = u = 2(xr-y)@s2_w
    if (t < 128) { int g = t >> 6, c = t & 63;
      float a = 0.f;
      if (g == 0) {
        #pragma unroll
        for (int o = 0; o < 128; ++o) {
          float r2 = fmaf(2.f, L1[o], (L2[o] + L3[o]) * (1.f / 64.f));
          a = fmaf(r2, s2_w[o * 64 + c], a);
        }
        M0[c] = a + 2.f * s2_b[c];
      } else {
        #pragma unroll
        for (int o = 0; o < 128; ++o)
          a = fmaf(2.f * (L0[o] - L3[o]), s2_w[o * 64 + c], a);
        M1[c] = a;
      } }
    __syncthreads();
    // Phase C: L0 = v@n1_w + n1_b ; L1 = u@n1_w
    { int g = t >> 7, o = t & 127;
      float a = 0.f;
      if (g == 0) {
        #pragma unroll
        for (int k = 0; k < 64; ++k) a = fmaf(M0[k], n1_w[k * 128 + o], a);
        L0[o] = a + n1_b[o];
      } else {
        #pragma unroll
        for (int k = 0; k < 64; ++k) a = fmaf(M1[k], n1_w[k * 128 + o], a);
        L1[o] = a;
      } }
    __syncthreads();
    // Phase D: M0 = c3 = L0@n2_w + n2_b ; M1 = un = L1@n2_w
    if (t < 128) { int g = t >> 6, c = t & 63;
      float a = 0.f;
      if (g == 0) {
        #pragma unroll
        for (int o = 0; o < 128; ++o) a = fmaf(L0[o], n2_w[o * 64 + c], a);
        M0[c] = a + n2_b[c];
      } else {
        #pragma unroll
        for (int o = 0; o < 128; ++o) a = fmaf(L1[o], n2_w[o * 64 + c], a);
        M1[c] = a;
      } }
    __syncthreads();
    // Phase E: L0 = ce = c3@E1r ; L1 = ne = (un + 128*c3)@E1s
    { int g = t >> 7, o = t & 127;
      float a = 0.f;
      if (g == 0) {
        #pragma unroll
        for (int k = 0; k < 64; ++k) a = fmaf(M0[k], e1_w[k * 128 + o], a);
        L0[o] = a;
      } else {
        #pragma unroll
        for (int k = 0; k < 64; ++k) {
          float nb = fmaf(128.f, M0[k], M1[k]);
          a = fmaf(nb, e1_w[(64 + k) * 128 + o], a);
        }
        L1[o] = a;
      } }
    __syncthreads();
    // Phase F: M0 = g3 = (2*ce + ne/64 + 2*e1_b)@e2_w + 2*e2_b
    if (t < 64) { float a = 0.f;
      #pragma unroll
      for (int o = 0; o < 128; ++o) {
        float gv = fmaf(L1[o], (1.f / 64.f), fmaf(2.f, L0[o], 2.f * e1_b[o]));
        a = fmaf(gv, e2_w[o * 64 + t], a);
      }
      M0[t] = a + 2.f * e2_b[t]; }
    __syncthreads();
    // Phase G: h3 = g3@f1_w + f1_b
    if (t < 128) { float a = 0.f;
      #pragma unroll
      for (int k = 0; k < 64; ++k) a = fmaf(M0[k], f1_w[k * 128 + t], a);
      ws[WS_H3 + b * 128 + t] = a + f1_b[t]; }
  }
}

// ---------------- K2: per-node fused MLP (LDS ~44 KB) ----------------
__global__ __launch_bounds__(256) void k_main(
    const float* __restrict__ h, const float* __restrict__ pos,
    const float* __restrict__ f2_w, const float* __restrict__ f2_b,
    const float* __restrict__ ws, float* __restrict__ out)
{
  __shared__ __align__(16) float lH1[64 * 128];  // [k][d]  32 KB
  __shared__ __align__(16) float lx[16 * 64];    // [n][k]
  __shared__ float lp[16 * 2];
  __shared__ __align__(16) float lh1[16 * 128];  // [n][k]
  int blk = blockIdx.x, t = threadIdx.x;
  int b = blk >> 3, j0 = (blk & 7) * 16;
  for (int i = t; i < 2048; i += 256) ((float4*)lH1)[i] = ((const float4*)(ws + WS_H1))[i];
  ((float4*)lx)[t] = ((const float4*)(h + (size_t)(b * 128 + j0) * 64))[t];
  if (t < 32) lp[t] = pos[(b * 128 + j0) * 2 + t];
  __syncthreads();
  // h1 = relu(x@H1 + p@H2 + h3)   (H2/h3 broadcast reads straight from L1/L2)
  {
    int d = t & 127, g = t >> 7, n0 = g * 8;
    float h3v = ws[WS_H3 + b * 128 + d];
    float h2a = ws[WS_H2 + d], h2b = ws[WS_H2 + 128 + d];
    float acc[8];
    #pragma unroll
    for (int i = 0; i < 8; ++i)
      acc[i] = h3v + lp[(n0 + i) * 2] * h2a + lp[(n0 + i) * 2 + 1] * h2b;
    #pragma unroll 4
    for (int k = 0; k < 64; k += 4) {
      float h0 = lH1[k * 128 + d], h1v = lH1[(k + 1) * 128 + d],
            h2v = lH1[(k + 2) * 128 + d], h3w = lH1[(k + 3) * 128 + d];
      #pragma unroll
      for (int i = 0; i < 8; ++i) {
        float4 xv = *(const float4*)&lx[(n0 + i) * 64 + k];
        acc[i] = fmaf(xv.x, h0, fmaf(xv.y, h1v, fmaf(xv.z, h2v, fmaf(xv.w, h3w, acc[i]))));
      }
    }
    #pragma unroll
    for (int i = 0; i < 8; ++i) lh1[(n0 + i) * 128 + d] = fmaxf(acc[i], 0.f);
  }
  __syncthreads();
  // out = relu(h1@f2_w + f2_b); f2_w/f2_b read from global (L2-resident)
  {
    int d = t & 63, g = t >> 6, n0 = g * 4;
    float acc[4];
    float bias = f2_b[d];
    #pragma unroll
    for (int i = 0; i < 4; ++i) acc[i] = bias;
    #pragma unroll 4
    for (int k = 0; k < 128; k += 4) {
      float f0 = f2_w[k * 64 + d], f1v = f2_w[(k + 1) * 64 + d],
            f2v = f2_w[(k + 2) * 64 + d], f3v = f2_w[(k + 3) * 64 + d];
      #pragma unroll
      for (int i = 0; i < 4; ++i) {
        float4 hv = *(const float4*)&lh1[(n0 + i) * 128 + k];
        acc[i] = fmaf(hv.x, f0, fmaf(hv.y, f1v, fmaf(hv.z, f2v, fmaf(hv.w, f3v, acc[i]))));
      }
    }
    #pragma unroll
    for (int i = 0; i < 4; ++i)
      out[(size_t)(b * 128 + j0 + n0 + i) * 64 + d] = fmaxf(acc[i], 0.f);
  }
}

extern "C" void kernel_launch(void* const* d_in, const int* in_sizes, int n_in,
                              void* d_out, int out_size, void* d_ws, size_t ws_size,
                              hipStream_t stream) {
  const float* h    = (const float*)d_in[0];
  const float* pos  = (const float*)d_in[1];
  const float* se_w = (const float*)d_in[2];
  const float* se_b = (const float*)d_in[3];
  const float* s1_w = (const float*)d_in[4];
  const float* s1_b = (const float*)d_in[5];
  const float* s2_w = (const float*)d_in[6];
  const float* s2_b = (const float*)d_in[7];
  const float* n1_w = (const float*)d_in[8];
  const float* n1_b = (const float*)d_in[9];
  const float* n2_w = (const float*)d_in[10];
  const float* n2_b = (const float*)d_in[11];
  const float* e1_w = (const float*)d_in[12];
  const float* e1_b = (const float*)d_in[13];
  const float* e2_w = (const float*)d_in[14];
  const float* e2_b = (const float*)d_in[15];
  const float* f1_w = (const float*)d_in[16];
  const float* f1_b = (const float*)d_in[17];
  const float* f2_w = (const float*)d_in[18];
  const float* f2_b = (const float*)d_in[19];
  float* ws = (float*)d_ws;
  float* out = (float*)d_out;

  hipLaunchKernelGGL(k_prep, dim3(64), dim3(256), 0, stream,
                     h, pos, se_w, se_b, s1_w, s1_b, s2_w, s2_b,
                     n1_w, n1_b, n2_w, n2_b, e1_w, e1_b, e2_w, e2_b,
                     f1_w, f1_b, ws);
  hipLaunchKernelGGL(k_main, dim3(256), dim3(256), 0, stream, h, pos, f2_w, f2_b, ws, out);
}